// Round 11
// baseline (370.516 us; speedup 1.0000x reference)
//
#include <hip/hip_runtime.h>

namespace {
constexpr int T = 512;
constexpr int BATCH = 512;
constexpr int D = 32;
constexpr int H = 64;
constexpr int THREADS = 128;  // 2 waves; lane pair (2j,2j+1) shares h-index j
constexpr int ROWS = 2;       // TWO rows per block, interleaved in-lane (shared weights)
}

typedef float v2f __attribute__((ext_vector_type(2)));
typedef float v4f __attribute__((ext_vector_type(4)));

__device__ __forceinline__ float rcpf(float x) { return __builtin_amdgcn_rcpf(x); }
__device__ __forceinline__ float sigm(float x) { return rcpf(1.0f + __expf(-x)); }
__device__ __forceinline__ float tanh_fast(float x) {
    // 1 - 2/(e^{2x}+1); saturates via inf/0 at extremes
    return 1.0f - 2.0f * rcpf(__expf(2.0f * x) + 1.0f);
}

// packed fp32 FMA on native 64-bit vector registers: no operand repacking
__device__ __forceinline__ void pk2(v2f& acc, v2f w, v2f v) {
    asm("v_pk_fma_f32 %0, %1, %2, %0" : "+v"(acc) : "v"(w), "v"(v));
}

// sum across a lane pair (l, l^1) — single DPP quad_perm [1,0,3,2], pure VALU
__device__ __forceinline__ float pair_sum(float v) {
    int i = __builtin_bit_cast(int, v);
    float t = __builtin_bit_cast(float,
        __builtin_amdgcn_update_dpp(0, i, 0xB1, 0xF, 0xF, true));
    return v + t;
}

__global__ __launch_bounds__(THREADS, 1) void gru_fused_kernel(
    const float* __restrict__ x,
    const float* __restrict__ w_ih_f, const float* __restrict__ w_hh_f,
    const float* __restrict__ b_ih_f, const float* __restrict__ b_hh_f,
    const float* __restrict__ w_ih_b, const float* __restrict__ b_ih_b,
    const float* __restrict__ b_hh_b,
    const float* __restrict__ fc1_w, const float* __restrict__ fc1_b,
    const float* __restrict__ fc2_w, const float* __restrict__ fc2_b,
    float* __restrict__ out)
{
    const int tid = threadIdx.x;
    const int j   = tid >> 1;     // h-index 0..63 — owns all 3 gates for this j
    const int q   = tid & 1;      // K-split half (= DPP pair lane)
    const int kh0 = q * 32;       // h-k slice [kh0, kh0+32)
    const int kx0 = q * 16;       // x-k slice [kx0, kx0+16)

    const int rowA = blockIdx.x * ROWS;
    const int rowB = rowA + 1;

    __shared__ v4f x_lds[T * D / 4];                       // 64 KB: row A staged
    __shared__ __align__(16) float h_lds[ROWS][2][H];      // per-row double-buffered h
    __shared__ float last_lds[ROWS][2 * H];

    // ---- per-lane weight slices in registers as v2f (144 floats, SHARED by both rows) ----
    v2f wr2[16], wz2[16], wn2[16], ur2[8], uz2[8], un2[8];
    {
        const v2f* pr = reinterpret_cast<const v2f*>(w_hh_f + (size_t)j * H + kh0);
        const v2f* pz = reinterpret_cast<const v2f*>(w_hh_f + (size_t)(H + j) * H + kh0);
        const v2f* pn = reinterpret_cast<const v2f*>(w_hh_f + (size_t)(2 * H + j) * H + kh0);
        #pragma unroll
        for (int m = 0; m < 16; ++m) { wr2[m] = pr[m]; wz2[m] = pz[m]; wn2[m] = pn[m]; }
        const v2f* qr = reinterpret_cast<const v2f*>(w_ih_f + (size_t)j * D + kx0);
        const v2f* qz = reinterpret_cast<const v2f*>(w_ih_f + (size_t)(H + j) * D + kx0);
        const v2f* qn = reinterpret_cast<const v2f*>(w_ih_f + (size_t)(2 * H + j) * D + kx0);
        #pragma unroll
        for (int m = 0; m < 8; ++m) { ur2[m] = qr[m]; uz2[m] = qz[m]; un2[m] = qn[m]; }
    }

    // biases: added exactly ONCE, AFTER the pair reduction
    const float pre_r  = b_ih_f[j]         + b_hh_f[j];
    const float pre_z  = b_ih_f[H + j]     + b_hh_f[H + j];
    const float pre_nx = b_ih_f[2 * H + j];
    const float pre_nh = b_hh_f[2 * H + j];

    const float* xrowA = x + (size_t)rowA * T * D;
    const float* xrowB = x + (size_t)rowB * T * D;

    // ---- stage row A's x into LDS (coalesced float4) ----
    {
        const v4f* xg = reinterpret_cast<const v4f*>(xrowA);
        #pragma unroll 4
        for (int i = tid; i < T * D / 4; i += THREADS) x_lds[i] = xg[i];
    }
    if (tid < H) { h_lds[0][0][tid] = 0.0f; h_lds[1][0][tid] = 0.0f; }
    __syncthreads();

    // ---- t=0 x partials: row A from LDS, row B from global; prefetch xB[1] ----
    v2f axrA = {0.f,0.f}, axzA = {0.f,0.f}, axnA = {0.f,0.f};
    {
        const v2f* xt2 = reinterpret_cast<const v2f*>(x_lds) + q * 8;
        #pragma unroll
        for (int m = 0; m < 8; ++m) {
            v2f xv = xt2[m];
            pk2(axrA, ur2[m], xv); pk2(axzA, uz2[m], xv); pk2(axnA, un2[m], xv);
        }
    }
    v2f axrB = {0.f,0.f}, axzB = {0.f,0.f}, axnB = {0.f,0.f};
    {
        const v2f* px = reinterpret_cast<const v2f*>(xrowB + kx0);
        #pragma unroll
        for (int m = 0; m < 8; ++m) {
            v2f xv = px[m];
            pk2(axrB, ur2[m], xv); pk2(axzB, uz2[m], xv); pk2(axnB, un2[m], xv);
        }
    }
    v4f nxB[4];   // xB[t+1] slice in registers (vmcnt queue rides across barriers)
    {
        const v4f* px = reinterpret_cast<const v4f*>(xrowB + D + kx0);
        nxB[0] = px[0]; nxB[1] = px[1]; nxB[2] = px[2]; nxB[3] = px[3];
    }

    float holdA = 0.0f, holdB = 0.0f;

    for (int t = 0; t < T; ++t) {
        const int cur = t & 1, nxt = cur ^ 1;

        // ---- row A h-dot (48 pk2) ----
        v2f hhA[16];
        {
            const v2f* hp = reinterpret_cast<const v2f*>(&h_lds[0][cur][kh0]);
            #pragma unroll
            for (int m = 0; m < 16; ++m) hhA[m] = hp[m];
        }
        v2f prA = axrA, pzA = axzA, nhA = {0.f,0.f};
        #pragma unroll
        for (int m = 0; m < 16; ++m) pk2(prA, wr2[m], hhA[m]);
        #pragma unroll
        for (int m = 0; m < 16; ++m) pk2(pzA, wz2[m], hhA[m]);
        #pragma unroll
        for (int m = 0; m < 16; ++m) pk2(nhA, wn2[m], hhA[m]);
        const v2f axnA_t = axnA;

        // ---- row B h-dot (48 pk2, independent chain — fills A's stalls) ----
        v2f hhB[16];
        {
            const v2f* hp = reinterpret_cast<const v2f*>(&h_lds[1][cur][kh0]);
            #pragma unroll
            for (int m = 0; m < 16; ++m) hhB[m] = hp[m];
        }
        v2f prB = axrB, pzB = axzB, nhB = {0.f,0.f};
        #pragma unroll
        for (int m = 0; m < 16; ++m) pk2(prB, wr2[m], hhB[m]);
        #pragma unroll
        for (int m = 0; m < 16; ++m) pk2(pzB, wz2[m], hhB[m]);
        #pragma unroll
        for (int m = 0; m < 16; ++m) pk2(nhB, wn2[m], hhB[m]);
        const v2f axnB_t = axnB;

        // ---- row A x-partials for t+1 (LDS) ----
        {
            const int tn = (t + 1) & (T - 1);
            const v2f* xt2 = reinterpret_cast<const v2f*>(x_lds) + tn * (D / 2) + q * 8;
            axrA = {0.f,0.f}; axzA = {0.f,0.f}; axnA = {0.f,0.f};
            #pragma unroll
            for (int m = 0; m < 8; ++m) {
                v2f xv = xt2[m];
                pk2(axrA, ur2[m], xv); pk2(axzA, uz2[m], xv); pk2(axnA, un2[m], xv);
            }
        }

        // ---- row B x-partials for t+1 (from prefetched registers) ----
        {
            axrB = {0.f,0.f}; axzB = {0.f,0.f}; axnB = {0.f,0.f};
            #pragma unroll
            for (int mm = 0; mm < 4; ++mm) {
                v2f lo = __builtin_shufflevector(nxB[mm], nxB[mm], 0, 1);
                v2f hi = __builtin_shufflevector(nxB[mm], nxB[mm], 2, 3);
                pk2(axrB, ur2[2*mm], lo); pk2(axrB, ur2[2*mm+1], hi);
                pk2(axzB, uz2[2*mm], lo); pk2(axzB, uz2[2*mm+1], hi);
                pk2(axnB, un2[2*mm], lo); pk2(axnB, un2[2*mm+1], hi);
            }
        }

        // ---- prefetch xB[t+2] from global (consumed next step) ----
        {
            const v4f* px = reinterpret_cast<const v4f*>(
                xrowB + ((t + 2) & (T - 1)) * D + kx0);
            nxB[0] = px[0]; nxB[1] = px[1]; nxB[2] = px[2]; nxB[3] = px[3];
        }

        // ---- pair reductions (pure-VALU DPP) ----
        const float vrA  = pair_sum(prA.x + prA.y);
        const float vzA  = pair_sum(pzA.x + pzA.y);
        const float vnhA = pair_sum(nhA.x + nhA.y);
        const float vnxA = pair_sum(axnA_t.x + axnA_t.y);
        const float vrB  = pair_sum(prB.x + prB.y);
        const float vzB  = pair_sum(pzB.x + pzB.y);
        const float vnhB = pair_sum(nhB.x + nhB.y);
        const float vnxB = pair_sum(axnB_t.x + axnB_t.y);

        // ---- gates + update, both rows (two independent trans chains) ----
        const float rA = sigm(vrA + pre_r);
        const float zA = sigm(vzA + pre_z);
        const float rB = sigm(vrB + pre_r);
        const float zB = sigm(vzB + pre_z);
        const float nA = tanh_fast(vnxA + pre_nx + rA * (vnhA + pre_nh));
        const float nB = tanh_fast(vnxB + pre_nx + rB * (vnhB + pre_nh));
        const float hnewA = nA + zA * (holdA - nA);
        const float hnewB = nB + zB * (holdB - nB);
        holdA = hnewA; holdB = hnewB;
        if (q == 0) { h_lds[0][nxt][j] = hnewA; h_lds[1][nxt][j] = hnewB; }
        __syncthreads();   // single barrier per step, 2 waves
    }

    // ---- epilogue: wave w handles row w ----
    const int wave = tid >> 6, lane = tid & 63;
    const float* xrow_w = (wave == 0) ? xrowA : xrowB;

    // backward direction: exactly ONE step from h0 = 0 on x[row][T-1][:]
    {
        const float* xT = xrow_w + (size_t)(T - 1) * D;
        float xr = b_ih_b[lane];
        float xz = b_ih_b[H + lane];
        float xn = b_ih_b[2 * H + lane];
        #pragma unroll
        for (int k = 0; k < D; ++k) {
            const float xv = xT[k];
            xr = fmaf(w_ih_b[(size_t)lane * D + k],           xv, xr);
            xz = fmaf(w_ih_b[(size_t)(H + lane) * D + k],     xv, xz);
            xn = fmaf(w_ih_b[(size_t)(2 * H + lane) * D + k], xv, xn);
        }
        const float r = sigm(xr + b_hh_b[lane]);
        const float z = sigm(xz + b_hh_b[H + lane]);
        const float n = tanh_fast(xn + r * b_hh_b[2 * H + lane]);
        last_lds[wave][H + lane] = (1.0f - z) * n;   // z*h0 = 0
    }
    // forward final state (T even -> buffer 0); loop's last __syncthreads()
    // made cross-wave h writes visible
    last_lds[wave][lane] = h_lds[wave][0][lane];
    // same-wave LDS write->read: in-order DS pipe, no barrier needed

    // head: h1 = leaky(fc1_w @ last + fc1_b); out = fc2_w @ h1 + fc2_b
    {
        float acc = fc1_b[lane];
        const float* w1 = fc1_w + (size_t)lane * (2 * H);
        #pragma unroll 8
        for (int c = 0; c < 2 * H; ++c) acc = fmaf(w1[c], last_lds[wave][c], acc);
        acc = (acc >= 0.0f) ? acc : 0.2f * acc;
        float red = acc * fc2_w[lane];
        #pragma unroll
        for (int off = 32; off > 0; off >>= 1)
            red += __shfl_down(red, off);
        if (lane == 0) out[rowA + wave] = red + fc2_b[0];
    }
}

extern "C" void kernel_launch(void* const* d_in, const int* in_sizes, int n_in,
                              void* d_out, int out_size, void* d_ws, size_t ws_size,
                              hipStream_t stream) {
    const float* x      = (const float*)d_in[0];
    const float* w_ih_f = (const float*)d_in[1];
    const float* w_hh_f = (const float*)d_in[2];
    const float* b_ih_f = (const float*)d_in[3];
    const float* b_hh_f = (const float*)d_in[4];
    const float* w_ih_b = (const float*)d_in[5];
    // d_in[6] = w_hh_b: unused (backward direction runs exactly one step from h0=0)
    const float* b_ih_b = (const float*)d_in[7];
    const float* b_hh_b = (const float*)d_in[8];
    const float* fc1_w  = (const float*)d_in[9];
    const float* fc1_b  = (const float*)d_in[10];
    const float* fc2_w  = (const float*)d_in[11];
    const float* fc2_b  = (const float*)d_in[12];
    float* out = (float*)d_out;

    gru_fused_kernel<<<BATCH / ROWS, THREADS, 0, stream>>>(
        x, w_ih_f, w_hh_f, b_ih_f, b_hh_f,
        w_ih_b, b_ih_b, b_hh_b,
        fc1_w, fc1_b, fc2_w, fc2_b, out);
}

// Round 12
// 229.364 us; speedup vs baseline: 1.6154x; 1.6154x over previous
//
#include <hip/hip_runtime.h>

namespace {
constexpr int T = 512;
constexpr int BATCH = 512;
constexpr int D = 32;
constexpr int H = 64;
constexpr int THREADS = 128;  // 2 waves/row; lane pair (2j,2j+1) shares h-index j
}

typedef float v2f __attribute__((ext_vector_type(2)));

__device__ __forceinline__ float rcpf(float x) { return __builtin_amdgcn_rcpf(x); }
__device__ __forceinline__ float sigm(float x) { return rcpf(1.0f + __expf(-x)); }
__device__ __forceinline__ float tanh_fast(float x) {
    // 1 - 2/(e^{2x}+1); saturates via inf/0 at extremes
    return 1.0f - 2.0f * rcpf(__expf(2.0f * x) + 1.0f);
}

// packed fp32 FMA on native 64-bit vector registers: no operand repacking
__device__ __forceinline__ void pk2(v2f& acc, v2f w, v2f v) {
    asm("v_pk_fma_f32 %0, %1, %2, %0" : "+v"(acc) : "v"(w), "v"(v));
}

// sum across a lane pair (l, l^1) — single DPP quad_perm [1,0,3,2], pure VALU
__device__ __forceinline__ float pair_sum(float v) {
    int i = __builtin_bit_cast(int, v);
    float t = __builtin_bit_cast(float,
        __builtin_amdgcn_update_dpp(0, i, 0xB1, 0xF, 0xF, true));
    return v + t;
}

// Residency pin: empty asm that "may modify" the weights each iteration.
// A post-asm reload from global would be illegal -> values must stay in VGPRs.
// (R10/R11 evidence: without this the allocator settles at 132 VGPR and
// rematerializes weight loads in-loop; weights need 144 floats resident.)
#define KEEP4(a, b, c, d) asm volatile("" : "+v"(a), "+v"(b), "+v"(c), "+v"(d))

__global__
__attribute__((amdgpu_flat_work_group_size(THREADS, THREADS)))
__attribute__((amdgpu_waves_per_eu(1, 1)))   // occupancy target = reality: 1 wave/EU
void gru_fused_kernel(
    const float* __restrict__ x,
    const float* __restrict__ w_ih_f, const float* __restrict__ w_hh_f,
    const float* __restrict__ b_ih_f, const float* __restrict__ b_hh_f,
    const float* __restrict__ w_ih_b, const float* __restrict__ b_ih_b,
    const float* __restrict__ b_hh_b,
    const float* __restrict__ fc1_w, const float* __restrict__ fc1_b,
    const float* __restrict__ fc2_w, const float* __restrict__ fc2_b,
    float* __restrict__ out)
{
    const int b   = blockIdx.x;   // batch row
    const int tid = threadIdx.x;
    const int j   = tid >> 1;     // h-index 0..63 — owns all 3 gates for this j
    const int q   = tid & 1;      // K-split half (= DPP pair lane)
    const int kh0 = q * 32;       // h-k slice [kh0, kh0+32)
    const int kx0 = q * 16;       // x-k slice [kx0, kx0+16)

    __shared__ v2f x_lds[T * D / 2];                 // 64 KB staged x row
    __shared__ __align__(16) float h_lds[2][H];      // double-buffered h
    __shared__ float last_lds[2 * H];

    // ---- per-lane weight slices in registers as native v2f (144 floats) ----
    v2f wr2[16], wz2[16], wn2[16], ur2[8], uz2[8], un2[8];
    {
        const v2f* pr = reinterpret_cast<const v2f*>(w_hh_f + (size_t)j * H + kh0);
        const v2f* pz = reinterpret_cast<const v2f*>(w_hh_f + (size_t)(H + j) * H + kh0);
        const v2f* pn = reinterpret_cast<const v2f*>(w_hh_f + (size_t)(2 * H + j) * H + kh0);
        #pragma unroll
        for (int m = 0; m < 16; ++m) { wr2[m] = pr[m]; wz2[m] = pz[m]; wn2[m] = pn[m]; }
        const v2f* qr = reinterpret_cast<const v2f*>(w_ih_f + (size_t)j * D + kx0);
        const v2f* qz = reinterpret_cast<const v2f*>(w_ih_f + (size_t)(H + j) * D + kx0);
        const v2f* qn = reinterpret_cast<const v2f*>(w_ih_f + (size_t)(2 * H + j) * D + kx0);
        #pragma unroll
        for (int m = 0; m < 8; ++m) { ur2[m] = qr[m]; uz2[m] = qz[m]; un2[m] = qn[m]; }
    }

    // biases: added exactly ONCE, AFTER the pair reduction
    const float pre_r  = b_ih_f[j]         + b_hh_f[j];
    const float pre_z  = b_ih_f[H + j]     + b_hh_f[H + j];
    const float pre_nx = b_ih_f[2 * H + j];
    const float pre_nh = b_hh_f[2 * H + j];

    // ---- stage x row into LDS (coalesced float4) ----
    {
        const float4* xg  = reinterpret_cast<const float4*>(x + (size_t)b * T * D);
        float4*       xl4 = reinterpret_cast<float4*>(x_lds);
        #pragma unroll 4
        for (int i = tid; i < T * D / 4; i += THREADS) xl4[i] = xg[i];
    }
    if (tid < H) h_lds[0][tid] = 0.0f;
    __syncthreads();

    // ---- x partials for t=0 (bias-free, unreduced) ----
    v2f axr = {0.f, 0.f}, axz = {0.f, 0.f}, axn = {0.f, 0.f};
    {
        const v2f* xt2 = x_lds + q * 8;   // t=0
        #pragma unroll
        for (int m = 0; m < 8; ++m) {
            v2f xv = xt2[m];
            pk2(axr, ur2[m], xv);
            pk2(axz, uz2[m], xv);
            pk2(axn, un2[m], xv);
        }
    }

    float hold = 0.0f;

    for (int t = 0; t < T; ++t) {
        const int cur = t & 1, nxt = cur ^ 1;

        // h slice: 32 floats as 16 v2f (contiguous -> ds_read_b128 bursts)
        v2f hh[16];
        {
            const v2f* hp = reinterpret_cast<const v2f*>(&h_lds[cur][kh0]);
            #pragma unroll
            for (int m = 0; m < 16; ++m) hh[m] = hp[m];
        }

        // h-dot seeded with this step's x partials: 48 pk2
        v2f pr = axr, pz = axz, nh = {0.f, 0.f};
        #pragma unroll
        for (int m = 0; m < 16; ++m) pk2(pr, wr2[m], hh[m]);
        #pragma unroll
        for (int m = 0; m < 16; ++m) pk2(pz, wz2[m], hh[m]);
        #pragma unroll
        for (int m = 0; m < 16; ++m) pk2(nh, wn2[m], hh[m]);
        const v2f axn_t = axn;   // n-gate x partial for THIS step

        // x partials for t+1 (independent of h — fills reduce/trans latency)
        {
            const int tn = (t + 1) & (T - 1);
            const v2f* xt2 = x_lds + tn * (D / 2) + q * 8;
            axr = {0.f, 0.f}; axz = {0.f, 0.f}; axn = {0.f, 0.f};
            #pragma unroll
            for (int m = 0; m < 8; ++m) {
                v2f xv = xt2[m];
                pk2(axr, ur2[m], xv);
                pk2(axz, uz2[m], xv);
                pk2(axn, un2[m], xv);
            }
        }

        // pair reduction: single DPP butterfly each, pure VALU
        const float vr  = pair_sum(pr.x + pr.y);
        const float vz  = pair_sum(pz.x + pz.y);
        const float vnh = pair_sum(nh.x + nh.y);
        const float vnx = pair_sum(axn_t.x + axn_t.y);

        const float r = sigm(vr + pre_r);
        const float z = sigm(vz + pre_z);
        const float n = tanh_fast(vnx + pre_nx + r * (vnh + pre_nh));
        const float hnew = n + z * (hold - n);   // (1-z)n + z*hold
        hold = hnew;
        if (q == 0) h_lds[nxt][j] = hnew;
        __syncthreads();   // single barrier per step, only 2 waves

        // pin the 36 weight v2fs in registers across the backedge
        KEEP4(wr2[0],  wr2[1],  wr2[2],  wr2[3]);
        KEEP4(wr2[4],  wr2[5],  wr2[6],  wr2[7]);
        KEEP4(wr2[8],  wr2[9],  wr2[10], wr2[11]);
        KEEP4(wr2[12], wr2[13], wr2[14], wr2[15]);
        KEEP4(wz2[0],  wz2[1],  wz2[2],  wz2[3]);
        KEEP4(wz2[4],  wz2[5],  wz2[6],  wz2[7]);
        KEEP4(wz2[8],  wz2[9],  wz2[10], wz2[11]);
        KEEP4(wz2[12], wz2[13], wz2[14], wz2[15]);
        KEEP4(wn2[0],  wn2[1],  wn2[2],  wn2[3]);
        KEEP4(wn2[4],  wn2[5],  wn2[6],  wn2[7]);
        KEEP4(wn2[8],  wn2[9],  wn2[10], wn2[11]);
        KEEP4(wn2[12], wn2[13], wn2[14], wn2[15]);
        KEEP4(ur2[0],  ur2[1],  ur2[2],  ur2[3]);
        KEEP4(ur2[4],  ur2[5],  ur2[6],  ur2[7]);
        KEEP4(uz2[0],  uz2[1],  uz2[2],  uz2[3]);
        KEEP4(uz2[4],  uz2[5],  uz2[6],  uz2[7]);
        KEEP4(un2[0],  un2[1],  un2[2],  un2[3]);
        KEEP4(un2[4],  un2[5],  un2[6],  un2[7]);
    }

    // ---- epilogue ----
    const int wave = tid >> 6, lane = tid & 63;

    // forward final state (T even -> buffer 0)
    if (wave == 0) last_lds[lane] = h_lds[T & 1][lane];

    // backward direction: exactly ONE step from h0 = 0 on x[b][T-1][:]
    if (wave == 1) {
        const float* xT = reinterpret_cast<const float*>(x_lds) + (T - 1) * D;
        const int jj = lane;
        float xr = b_ih_b[jj];
        float xz = b_ih_b[H + jj];
        float xn = b_ih_b[2 * H + jj];
        #pragma unroll
        for (int k = 0; k < D; ++k) {
            const float xv = xT[k];
            xr = fmaf(w_ih_b[(size_t)jj * D + k],           xv, xr);
            xz = fmaf(w_ih_b[(size_t)(H + jj) * D + k],     xv, xz);
            xn = fmaf(w_ih_b[(size_t)(2 * H + jj) * D + k], xv, xn);
        }
        const float r = sigm(xr + b_hh_b[jj]);
        const float z = sigm(xz + b_hh_b[H + jj]);
        const float n = tanh_fast(xn + r * b_hh_b[2 * H + jj]);
        last_lds[H + jj] = (1.0f - z) * n;   // z*h0 = 0
    }
    __syncthreads();

    // head: h1 = leaky(fc1_w @ last + fc1_b); out = fc2_w @ h1 + fc2_b
    if (wave == 0) {
        float acc = fc1_b[lane];
        const float* w1 = fc1_w + (size_t)lane * (2 * H);
        #pragma unroll 8
        for (int c = 0; c < 2 * H; ++c) acc = fmaf(w1[c], last_lds[c], acc);
        acc = (acc >= 0.0f) ? acc : 0.2f * acc;
        float red = acc * fc2_w[lane];
        #pragma unroll
        for (int off = 32; off > 0; off >>= 1)
            red += __shfl_down(red, off);
        if (lane == 0) out[b] = red + fc2_b[0];
    }
}

extern "C" void kernel_launch(void* const* d_in, const int* in_sizes, int n_in,
                              void* d_out, int out_size, void* d_ws, size_t ws_size,
                              hipStream_t stream) {
    const float* x      = (const float*)d_in[0];
    const float* w_ih_f = (const float*)d_in[1];
    const float* w_hh_f = (const float*)d_in[2];
    const float* b_ih_f = (const float*)d_in[3];
    const float* b_hh_f = (const float*)d_in[4];
    const float* w_ih_b = (const float*)d_in[5];
    // d_in[6] = w_hh_b: unused (backward direction runs exactly one step from h0=0)
    const float* b_ih_b = (const float*)d_in[7];
    const float* b_hh_b = (const float*)d_in[8];
    const float* fc1_w  = (const float*)d_in[9];
    const float* fc1_b  = (const float*)d_in[10];
    const float* fc2_w  = (const float*)d_in[11];
    const float* fc2_b  = (const float*)d_in[12];
    float* out = (float*)d_out;

    gru_fused_kernel<<<BATCH, THREADS, 0, stream>>>(
        x, w_ih_f, w_hh_f, b_ih_f, b_hh_f,
        w_ih_b, b_ih_b, b_hh_b,
        fc1_w, fc1_b, fc2_w, fc2_b, out);
}